// Round 2
// baseline (196.268 us; speedup 1.0000x reference)
//
#include <hip/hip_runtime.h>

// UpFirDn 2x downsample: depthwise 4x4 FIR (separable binomial), stride 2,
// pad (1,1). x: (16,512,64,64) f32 -> out: (16,512,32,32) f32.
//
// One block per (n,c) image. Separable two-pass through LDS.
// R1 change: stage-1 lanes are contiguous along the image row (16 lanes x
// float4 = one 64-col row), so global loads are perfectly coalesced
// (16 B/lane, 1 KiB/wave-instr). The 1-element horizontal halo comes from
// __shfl within the 16-lane row group; group edges coincide with the
// zero-pad columns (-1, 64).

#define IH 64
#define IW 64
#define OHN 32
#define OWN 32
#define HP 34   // hbuf pitch: even (aligned float2 writes), (2y+ow)%32 -> 2-way (free)

__global__ __launch_bounds__(256) void upfirdn_down2_kernel(
    const float* __restrict__ x, const float* __restrict__ kk,
    float* __restrict__ out)
{
    __shared__ float hbuf[IH * HP];  // 64*34*4 = 8704 B

    const int t = threadIdx.x;
    const int img = blockIdx.x;
    const float4* __restrict__ x4 = (const float4*)(x + (size_t)img * (IH * IW));
    float* __restrict__ oi = out + (size_t)img * (OHN * OWN);

    // --- separable weights from the (flipped) 4x4 kernel ------------------
    // kh[j] multiplies input col 2*ow-1+j; kv[i] multiplies h row 2*oh-1+i.
    float km[16];
#pragma unroll
    for (int i = 0; i < 16; ++i) km[i] = kk[i];
    const float kh0 = km[3] + km[7] + km[11] + km[15];
    const float kh1 = km[2] + km[6] + km[10] + km[14];
    const float kh2 = km[1] + km[5] + km[9]  + km[13];
    const float kh3 = km[0] + km[4] + km[8]  + km[12];
    const float kv0 = km[12] + km[13] + km[14] + km[15];
    const float kv1 = km[8]  + km[9]  + km[10] + km[11];
    const float kv2 = km[4]  + km[5]  + km[6]  + km[7];
    const float kv3 = km[0]  + km[1]  + km[2]  + km[3];

    // --- stage 1: coalesced load + horizontal filter into LDS -------------
    // iter i: lane layout c = t&15 (float4 col), row = (t>>4) + 16*i.
    // Each lane produces h[row][2c], h[row][2c+1].
    const int c = t & 15;
    float4 a[4];
#pragma unroll
    for (int i = 0; i < 4; ++i) a[i] = x4[t + 256 * i];

#pragma unroll
    for (int i = 0; i < 4; ++i) {
        const int row = (t >> 4) + 16 * i;
        float left  = __shfl_up(a[i].w, 1, 16);   // col 4c-1 (lane L-1's .w)
        float right = __shfl_down(a[i].x, 1, 16); // col 4c+4 (lane L+1's .x)
        if (c == 0)  left = 0.0f;    // zero-pad col -1
        if (c == 15) right = 0.0f;   // zero-pad col 64
        // ow = 2c   needs cols 4c-1..4c+2 : left, x, y, z
        // ow = 2c+1 needs cols 4c+1..4c+4 : y, z, w, right
        const float h0 = kh0 * left   + kh1 * a[i].x + kh2 * a[i].y + kh3 * a[i].z;
        const float h1 = kh0 * a[i].y + kh1 * a[i].z + kh2 * a[i].w + kh3 * right;
        float2* hb = (float2*)&hbuf[row * HP + 2 * c];
        *hb = make_float2(h0, h1);
    }
    __syncthreads();

    // --- stage 2: vertical filter, 4 outputs per thread -------------------
    // thread t: ow = t&31, group g = t>>5 -> oh in [4g, 4g+4)
    // needs h rows [8g-1, 8g+8]: 10 reads shared across the 4 outputs.
    {
        const int ow = t & 31;
        const int g = t >> 5;
        const int ybase = 8 * g - 1;
        float hr[10];
#pragma unroll
        for (int r = 0; r < 10; ++r) {
            const int yy = ybase + r;
            hr[r] = (yy >= 0 && yy < IH) ? hbuf[yy * HP + ow] : 0.0f;
        }
#pragma unroll
        for (int m = 0; m < 4; ++m) {
            const float o = kv0 * hr[2 * m] + kv1 * hr[2 * m + 1]
                          + kv2 * hr[2 * m + 2] + kv3 * hr[2 * m + 3];
            oi[(4 * g + m) * OWN + ow] = o;
        }
    }
}

extern "C" void kernel_launch(void* const* d_in, const int* in_sizes, int n_in,
                              void* d_out, int out_size, void* d_ws, size_t ws_size,
                              hipStream_t stream) {
    const float* x = (const float*)d_in[0];
    const float* k = (const float*)d_in[1];
    float* out = (float*)d_out;
    const int n_img = in_sizes[0] / (IH * IW);  // 16*512 = 8192
    upfirdn_down2_kernel<<<n_img, 256, 0, stream>>>(x, k, out);
}